// Round 1
// baseline (988.254 us; speedup 1.0000x reference)
//
#include <hip/hip_runtime.h>

#define D_MODEL 1024
#define D_FF    4096
#define N_EXP   8
#define BM 128
#define BN 128
#define BKT 64

typedef __attribute__((ext_vector_type(8))) short bf16x8;
typedef __attribute__((ext_vector_type(4))) float f32x4;

__device__ __forceinline__ unsigned short f2bf(float f) {
  union { float f; unsigned u; } v; v.f = f;
  unsigned r = v.u + 0x7FFFu + ((v.u >> 16) & 1u);
  return (unsigned short)(r >> 16);
}

// ---------------- x fp32 -> bf16 ----------------
__global__ void convert_x_kernel(const float* __restrict__ x,
                                 unsigned short* __restrict__ xb, int total8) {
  int i = blockIdx.x * blockDim.x + threadIdx.x;
  if (i >= total8) return;
  const float4* src = (const float4*)x + (size_t)i * 2;
  float4 a = src[0], b = src[1];
  ushort4 lo, hi;
  lo.x = f2bf(a.x); lo.y = f2bf(a.y); lo.z = f2bf(a.z); lo.w = f2bf(a.w);
  hi.x = f2bf(b.x); hi.y = f2bf(b.y); hi.z = f2bf(b.z); hi.w = f2bf(b.w);
  ushort4* dst = (ushort4*)xb + (size_t)i * 2;
  dst[0] = lo; dst[1] = hi;
}

// ---------------- gating: 1 wave per token ----------------
__global__ void gating_kernel(const float* __restrict__ x,
                              const float* __restrict__ Wg,
                              const float* __restrict__ bg,
                              float* __restrict__ gate_out,
                              int* __restrict__ cnt,
                              int* __restrict__ tokIdx,
                              float* __restrict__ tokW, int T) {
  int wv = threadIdx.x >> 6, lane = threadIdx.x & 63;
  int t = blockIdx.x * 4 + wv;
  if (t >= T) return;
  const float* xr = x + (size_t)t * D_MODEL + lane * 16;
  float acc[N_EXP];
  #pragma unroll
  for (int e = 0; e < N_EXP; e++) acc[e] = 0.f;
  #pragma unroll
  for (int q = 0; q < 4; q++) {
    float4 xv = *(const float4*)(xr + q * 4);
    #pragma unroll
    for (int r = 0; r < 4; r++) {
      float xs = ((const float*)&xv)[r];
      const float* wrow = Wg + (size_t)(lane * 16 + q * 4 + r) * N_EXP;
      float4 wa = *(const float4*)wrow;
      float4 wb = *(const float4*)(wrow + 4);
      acc[0] += xs * wa.x; acc[1] += xs * wa.y; acc[2] += xs * wa.z; acc[3] += xs * wa.w;
      acc[4] += xs * wb.x; acc[5] += xs * wb.y; acc[6] += xs * wb.z; acc[7] += xs * wb.w;
    }
  }
  #pragma unroll
  for (int off = 32; off > 0; off >>= 1) {
    #pragma unroll
    for (int e = 0; e < N_EXP; e++) acc[e] += __shfl_xor(acc[e], off);
  }
  if (lane == 0) {
    float l[N_EXP], p[N_EXP];
    float m = -1e30f;
    #pragma unroll
    for (int e = 0; e < N_EXP; e++) { l[e] = acc[e] + bg[e]; m = fmaxf(m, l[e]); }
    float s = 0.f;
    #pragma unroll
    for (int e = 0; e < N_EXP; e++) { p[e] = __expf(l[e] - m); s += p[e]; }
    float inv = 1.f / s;
    #pragma unroll
    for (int e = 0; e < N_EXP; e++) { p[e] *= inv; gate_out[(size_t)t * N_EXP + e] = p[e]; }
    int e1 = 0;
    #pragma unroll
    for (int e = 1; e < N_EXP; e++) if (p[e] > p[e1]) e1 = e;
    int e2 = (e1 == 0) ? 1 : 0;
    #pragma unroll
    for (int e = 0; e < N_EXP; e++) if (e != e1 && p[e] > p[e2]) e2 = e;
    int pos = atomicAdd(cnt + e1, 1);
    tokIdx[(size_t)e1 * T + pos] = t; tokW[(size_t)e1 * T + pos] = p[e1];
    pos = atomicAdd(cnt + e2, 1);
    tokIdx[(size_t)e2 * T + pos] = t; tokW[(size_t)e2 * T + pos] = p[e2];
  }
}

// ---------------- schedule: build row-tile table ----------------
__global__ void schedule_kernel(const int* __restrict__ cnt, int* __restrict__ meta,
                                int* __restrict__ tE, int* __restrict__ tB,
                                int* __restrict__ tV, int T, int maxTiles) {
  if (threadIdx.x != 0 || blockIdx.x != 0) return;
  int t = 0;
  for (int e = 0; e < N_EXP; e++) {
    int c = cnt[e];
    for (int r = 0; r < c && t < maxTiles; r += BM) {
      tE[t] = e; tB[t] = e * T + r; tV[t] = min(BM, c - r); t++;
    }
  }
  meta[0] = t;
}

// ---------------- GEMM1: h = relu(x_bf16 @ W1 + b1)  (grouped) ----------------
__global__ __launch_bounds__(256)
void gemm1_kernel(const unsigned short* __restrict__ xb,
                  const float* __restrict__ W1, const float* __restrict__ b1,
                  const int* __restrict__ meta,
                  const int* __restrict__ tE, const int* __restrict__ tB,
                  const int* __restrict__ tV, const int* __restrict__ tokIdx,
                  unsigned short* __restrict__ h, int FFC, int chunk_off) {
  __shared__ unsigned short As[BM * 64];
  __shared__ unsigned short Bs[BN * 64];
  __shared__ int stok[BM];

  int tile = blockIdx.x;
  if (tile >= meta[0]) return;
  int e = tE[tile], base = tB[tile], valid = tV[tile];
  int nb = blockIdx.y * BN;
  int tid = threadIdx.x;

  if (tid < BM) {
    int r = tid < valid ? tid : (valid - 1);
    stok[tid] = tokIdx[base + r];
  }
  __syncthreads();

  const float* W1e = W1 + (size_t)e * D_MODEL * D_FF;

  int w = tid >> 6, lane = tid & 63;
  int wr = w >> 1, wc = w & 1;
  int l15 = lane & 15, l4 = lane >> 4;

  int aIdx[2][4], bIdx[2][4];
  #pragma unroll
  for (int kk = 0; kk < 2; kk++) {
    #pragma unroll
    for (int m = 0; m < 4; m++) {
      int row = wr * 64 + m * 16 + l15;
      int kg = kk * 4 + l4;
      aIdx[kk][m] = row * 64 + (((kg + row) & 7) << 3);
      int col = wc * 64 + m * 16 + l15;
      bIdx[kk][m] = col * 64 + (((kg + (col >> 2) + col) & 7) << 3);
    }
  }
  int arow = tid >> 3, akg = tid & 7;
  int aw[4];
  #pragma unroll
  for (int p = 0; p < 4; p++) {
    int row = arow + p * 32;
    aw[p] = row * 64 + (((akg + row) & 7) << 3);
  }
  int bn4 = tid & 31, bkq0 = tid >> 5;

  f32x4 acc[4][4];
  #pragma unroll
  for (int m = 0; m < 4; m++)
    #pragma unroll
    for (int n = 0; n < 4; n++) acc[m][n] = (f32x4){0.f, 0.f, 0.f, 0.f};

  const int KT = D_MODEL / BKT;
  for (int kt = 0; kt < KT; kt++) {
    #pragma unroll
    for (int p = 0; p < 4; p++) {
      int row = arow + p * 32;
      const unsigned short* src = xb + (size_t)stok[row] * D_MODEL + kt * BKT + akg * 8;
      *(uint4*)&As[aw[p]] = *(const uint4*)src;
    }
    #pragma unroll
    for (int u = 0; u < 2; u++) {
      int kq = bkq0 + u * 8;
      const float* wsrc = W1e + (size_t)(kt * BKT + kq * 4) * D_FF + (chunk_off + nb + bn4 * 4);
      float4 f0 = *(const float4*)wsrc;
      float4 f1 = *(const float4*)(wsrc + D_FF);
      float4 f2 = *(const float4*)(wsrc + 2 * D_FF);
      float4 f3 = *(const float4*)(wsrc + 3 * D_FF);
      #pragma unroll
      for (int i = 0; i < 4; i++) {
        ushort4 pk;
        pk.x = f2bf(((const float*)&f0)[i]);
        pk.y = f2bf(((const float*)&f1)[i]);
        pk.z = f2bf(((const float*)&f2)[i]);
        pk.w = f2bf(((const float*)&f3)[i]);
        int n = bn4 * 4 + i;
        int kl = kq * 4;
        int idx = n * 64 + ((((kq >> 1) + (n >> 2) + n) & 7) << 3) + (kl & 7);
        *(ushort4*)&Bs[idx] = pk;
      }
    }
    __syncthreads();
    #pragma unroll
    for (int kk = 0; kk < 2; kk++) {
      bf16x8 a[4], b[4];
      #pragma unroll
      for (int m = 0; m < 4; m++) a[m] = *(const bf16x8*)&As[aIdx[kk][m]];
      #pragma unroll
      for (int n = 0; n < 4; n++) b[n] = *(const bf16x8*)&Bs[bIdx[kk][n]];
      #pragma unroll
      for (int m = 0; m < 4; m++)
        #pragma unroll
        for (int n = 0; n < 4; n++)
          acc[m][n] = __builtin_amdgcn_mfma_f32_16x16x32_bf16(a[m], b[n], acc[m][n], 0, 0, 0);
    }
    __syncthreads();
  }

  #pragma unroll
  for (int n = 0; n < 4; n++) {
    int colc = nb + wc * 64 + n * 16 + l15;
    float bias = b1[(size_t)e * D_FF + chunk_off + colc];
    #pragma unroll
    for (int m = 0; m < 4; m++) {
      #pragma unroll
      for (int r = 0; r < 4; r++) {
        int row = wr * 64 + m * 16 + l4 * 4 + r;
        float v = acc[m][n][r] + bias;
        v = v > 0.f ? v : 0.f;
        h[(size_t)(tile * BM + row) * FFC + colc] = f2bf(v);
      }
    }
  }
}

// ---------------- GEMM2: out += w * (h @ W2 + b2)  (grouped, scatter) ----------------
__global__ __launch_bounds__(256)
void gemm2_kernel(const unsigned short* __restrict__ h,
                  const float* __restrict__ W2, const float* __restrict__ b2,
                  const int* __restrict__ meta,
                  const int* __restrict__ tE, const int* __restrict__ tB,
                  const int* __restrict__ tV, const int* __restrict__ tokIdx,
                  const float* __restrict__ tokW,
                  float* __restrict__ out, int FFC, int chunk_off) {
  __shared__ unsigned short As[BM * 64];
  __shared__ unsigned short Bs[BN * 64];
  __shared__ int stok[BM];
  __shared__ float sw[BM];

  int tile = blockIdx.x;
  if (tile >= meta[0]) return;
  int e = tE[tile], base = tB[tile], valid = tV[tile];
  int nb = blockIdx.y * BN;
  int tid = threadIdx.x;

  if (tid < BM) {
    int r = tid < valid ? tid : (valid - 1);
    stok[tid] = tokIdx[base + r];
    sw[tid] = tokW[base + r];
  }
  __syncthreads();

  const float* W2e = W2 + (size_t)e * D_FF * D_MODEL;

  int w = tid >> 6, lane = tid & 63;
  int wr = w >> 1, wc = w & 1;
  int l15 = lane & 15, l4 = lane >> 4;

  int aIdx[2][4], bIdx[2][4];
  #pragma unroll
  for (int kk = 0; kk < 2; kk++) {
    #pragma unroll
    for (int m = 0; m < 4; m++) {
      int row = wr * 64 + m * 16 + l15;
      int kg = kk * 4 + l4;
      aIdx[kk][m] = row * 64 + (((kg + row) & 7) << 3);
      int col = wc * 64 + m * 16 + l15;
      bIdx[kk][m] = col * 64 + (((kg + (col >> 2) + col) & 7) << 3);
    }
  }
  int arow = tid >> 3, akg = tid & 7;
  int aw[4];
  #pragma unroll
  for (int p = 0; p < 4; p++) {
    int row = arow + p * 32;
    aw[p] = row * 64 + (((akg + row) & 7) << 3);
  }
  int bn4 = tid & 31, bkq0 = tid >> 5;

  f32x4 acc[4][4];
  #pragma unroll
  for (int m = 0; m < 4; m++)
    #pragma unroll
    for (int n = 0; n < 4; n++) acc[m][n] = (f32x4){0.f, 0.f, 0.f, 0.f};

  const int KT = FFC / BKT;
  for (int kt = 0; kt < KT; kt++) {
    #pragma unroll
    for (int p = 0; p < 4; p++) {
      int row = arow + p * 32;
      const unsigned short* src = h + (size_t)(tile * BM + row) * FFC + kt * BKT + akg * 8;
      *(uint4*)&As[aw[p]] = *(const uint4*)src;
    }
    #pragma unroll
    for (int u = 0; u < 2; u++) {
      int kq = bkq0 + u * 8;
      const float* wsrc = W2e + (size_t)(chunk_off + kt * BKT + kq * 4) * D_MODEL + (nb + bn4 * 4);
      float4 f0 = *(const float4*)wsrc;
      float4 f1 = *(const float4*)(wsrc + D_MODEL);
      float4 f2 = *(const float4*)(wsrc + 2 * D_MODEL);
      float4 f3 = *(const float4*)(wsrc + 3 * D_MODEL);
      #pragma unroll
      for (int i = 0; i < 4; i++) {
        ushort4 pk;
        pk.x = f2bf(((const float*)&f0)[i]);
        pk.y = f2bf(((const float*)&f1)[i]);
        pk.z = f2bf(((const float*)&f2)[i]);
        pk.w = f2bf(((const float*)&f3)[i]);
        int n = bn4 * 4 + i;
        int kl = kq * 4;
        int idx = n * 64 + ((((kq >> 1) + (n >> 2) + n) & 7) << 3) + (kl & 7);
        *(ushort4*)&Bs[idx] = pk;
      }
    }
    __syncthreads();
    #pragma unroll
    for (int kk = 0; kk < 2; kk++) {
      bf16x8 a[4], b[4];
      #pragma unroll
      for (int m = 0; m < 4; m++) a[m] = *(const bf16x8*)&As[aIdx[kk][m]];
      #pragma unroll
      for (int n = 0; n < 4; n++) b[n] = *(const bf16x8*)&Bs[bIdx[kk][n]];
      #pragma unroll
      for (int m = 0; m < 4; m++)
        #pragma unroll
        for (int n = 0; n < 4; n++)
          acc[m][n] = __builtin_amdgcn_mfma_f32_16x16x32_bf16(a[m], b[n], acc[m][n], 0, 0, 0);
    }
    __syncthreads();
  }

  int addBias = (chunk_off == 0) ? 1 : 0;
  #pragma unroll
  for (int n = 0; n < 4; n++) {
    int colg = nb + wc * 64 + n * 16 + l15;
    float bias = addBias ? b2[(size_t)e * D_MODEL + colg] : 0.f;
    #pragma unroll
    for (int m = 0; m < 4; m++) {
      #pragma unroll
      for (int r = 0; r < 4; r++) {
        int row = wr * 64 + m * 16 + l4 * 4 + r;
        if (row < valid) {
          float v = (acc[m][n][r] + bias) * sw[row];
          atomicAdd(out + (size_t)stok[row] * D_MODEL + colg, v);
        }
      }
    }
  }
}

// ---------------- host ----------------
extern "C" void kernel_launch(void* const* d_in, const int* in_sizes, int n_in,
                              void* d_out, int out_size, void* d_ws, size_t ws_size,
                              hipStream_t stream) {
  const float* x  = (const float*)d_in[0];
  const float* W1 = (const float*)d_in[1];
  const float* b1 = (const float*)d_in[2];
  const float* W2 = (const float*)d_in[3];
  const float* b2 = (const float*)d_in[4];
  const float* Wg = (const float*)d_in[5];
  const float* bg = (const float*)d_in[6];

  int T = in_sizes[0] / D_MODEL;  // 8192
  float* out = (float*)d_out;
  float* gate_out = out + (size_t)T * D_MODEL;

  char* ws = (char*)d_ws;
  int* cnt  = (int*)(ws + 0);
  int* meta = (int*)(ws + 64);
  int* tE   = (int*)(ws + 128);
  int* tB   = (int*)(ws + 1024);
  int* tV   = (int*)(ws + 2048);
  size_t off = 4096;
  int* tokIdx = (int*)(ws + off);   off += (size_t)N_EXP * T * 4;
  float* tokW = (float*)(ws + off); off += (size_t)N_EXP * T * 4;
  unsigned short* xb = (unsigned short*)(ws + off); off += (size_t)T * D_MODEL * 2;
  off = (off + 255) & ~(size_t)255;
  unsigned short* h = (unsigned short*)(ws + off);

  int maxTiles = (2 * T) / BM + N_EXP;  // 136
  int FFC = D_FF;
  while (FFC > 256 && off + (size_t)maxTiles * BM * FFC * 2 > ws_size) FFC >>= 1;

  hipMemsetAsync(d_out, 0, (size_t)T * D_MODEL * sizeof(float), stream);
  hipMemsetAsync(cnt, 0, N_EXP * sizeof(int), stream);

  int total8 = T * D_MODEL / 8;
  convert_x_kernel<<<(total8 + 255) / 256, 256, 0, stream>>>(x, xb, total8);
  gating_kernel<<<(T + 3) / 4, 256, 0, stream>>>(x, Wg, bg, gate_out, cnt, tokIdx, tokW, T);
  schedule_kernel<<<1, 64, 0, stream>>>(cnt, meta, tE, tB, tV, T, maxTiles);

  for (int c = 0; c * FFC < D_FF; c++) {
    gemm1_kernel<<<dim3(maxTiles, FFC / BN), 256, 0, stream>>>(
        xb, W1, b1, meta, tE, tB, tV, tokIdx, h, FFC, c * FFC);
    gemm2_kernel<<<dim3(maxTiles, D_MODEL / BN), 256, 0, stream>>>(
        h, W2, b2, meta, tE, tB, tV, tokIdx, tokW, out, FFC, c * FFC);
  }
}

// Round 2
// 794.649 us; speedup vs baseline: 1.2436x; 1.2436x over previous
//
#include <hip/hip_runtime.h>

#define D_MODEL 1024
#define D_FF    4096
#define N_EXP   8
#define BM 128
#define BN 128
#define BK 64

typedef __attribute__((ext_vector_type(8))) short bf16x8;
typedef __attribute__((ext_vector_type(4))) float f32x4;
typedef unsigned int u32;
typedef unsigned short ushortT;

__device__ __forceinline__ unsigned short f2bf(float f) {
  union { float f; unsigned u; } v; v.f = f;
  unsigned r = v.u + 0x7FFFu + ((v.u >> 16) & 1u);
  return (unsigned short)(r >> 16);
}

__device__ __forceinline__ void gl_lds16(const void* g, void* l) {
  __builtin_amdgcn_global_load_lds((const __attribute__((address_space(1))) u32*)g,
                                   (__attribute__((address_space(3))) u32*)l, 16, 0, 0);
}

// ---------------- x fp32 -> bf16 ----------------
__global__ void convert_x_kernel(const float* __restrict__ x,
                                 unsigned short* __restrict__ xb, int total8) {
  int i = blockIdx.x * blockDim.x + threadIdx.x;
  if (i >= total8) return;
  const float4* src = (const float4*)x + (size_t)i * 2;
  float4 a = src[0], b = src[1];
  ushort4 lo, hi;
  lo.x = f2bf(a.x); lo.y = f2bf(a.y); lo.z = f2bf(a.z); lo.w = f2bf(a.w);
  hi.x = f2bf(b.x); hi.y = f2bf(b.y); hi.z = f2bf(b.z); hi.w = f2bf(b.w);
  ushort4* dst = (ushort4*)xb + (size_t)i * 2;
  dst[0] = lo; dst[1] = hi;
}

// ---------------- transpose + convert W -> bf16 [e][n][k] ----------------
__global__ __launch_bounds__(256)
void transpose_convert_kernel(const float* __restrict__ src, unsigned short* __restrict__ dst,
                              int Ksub, int Nsrc, int k0, int n0, int Nchunk,
                              unsigned long long eStride) {
  __shared__ unsigned short s[64][65];  // s[n][k]
  int e = blockIdx.z;
  int kb = blockIdx.x * 64, nb = blockIdx.y * 64;
  const float* se = src + (size_t)e * eStride;
  unsigned short* de = dst + (size_t)e * Nchunk * Ksub;
  int tid = threadIdx.x;
  int lk = tid >> 4, ln = (tid & 15) * 4;
  #pragma unroll
  for (int p = 0; p < 4; p++) {
    int k = lk + p * 16;
    float4 v = *(const float4*)(se + (size_t)(k0 + kb + k) * Nsrc + (n0 + nb + ln));
    s[ln + 0][k] = f2bf(v.x);
    s[ln + 1][k] = f2bf(v.y);
    s[ln + 2][k] = f2bf(v.z);
    s[ln + 3][k] = f2bf(v.w);
  }
  __syncthreads();
  #pragma unroll
  for (int c = 0; c < 2; c++) {
    int id = tid + c * 256;
    int n = id >> 3, kc = id & 7;
    unsigned short u[8];
    #pragma unroll
    for (int j = 0; j < 8; j++) u[j] = s[n][kc * 8 + j];
    *(uint4*)(de + (size_t)(nb + n) * Ksub + kb + kc * 8) = *(const uint4*)u;
  }
}

// ---------------- gating: 1 wave per token ----------------
__global__ void gating_kernel(const float* __restrict__ x,
                              const float* __restrict__ Wg,
                              const float* __restrict__ bg,
                              float* __restrict__ gate_out,
                              int* __restrict__ cnt,
                              int* __restrict__ tokIdx,
                              float* __restrict__ tokW, int T) {
  int wv = threadIdx.x >> 6, lane = threadIdx.x & 63;
  int t = blockIdx.x * 4 + wv;
  if (t >= T) return;
  const float* xr = x + (size_t)t * D_MODEL + lane * 16;
  float acc[N_EXP];
  #pragma unroll
  for (int e = 0; e < N_EXP; e++) acc[e] = 0.f;
  #pragma unroll
  for (int q = 0; q < 4; q++) {
    float4 xv = *(const float4*)(xr + q * 4);
    #pragma unroll
    for (int r = 0; r < 4; r++) {
      float xs = ((const float*)&xv)[r];
      const float* wrow = Wg + (size_t)(lane * 16 + q * 4 + r) * N_EXP;
      float4 wa = *(const float4*)wrow;
      float4 wb = *(const float4*)(wrow + 4);
      acc[0] += xs * wa.x; acc[1] += xs * wa.y; acc[2] += xs * wa.z; acc[3] += xs * wa.w;
      acc[4] += xs * wb.x; acc[5] += xs * wb.y; acc[6] += xs * wb.z; acc[7] += xs * wb.w;
    }
  }
  #pragma unroll
  for (int off = 32; off > 0; off >>= 1) {
    #pragma unroll
    for (int e = 0; e < N_EXP; e++) acc[e] += __shfl_xor(acc[e], off);
  }
  if (lane == 0) {
    float l[N_EXP], p[N_EXP];
    float m = -1e30f;
    #pragma unroll
    for (int e = 0; e < N_EXP; e++) { l[e] = acc[e] + bg[e]; m = fmaxf(m, l[e]); }
    float s = 0.f;
    #pragma unroll
    for (int e = 0; e < N_EXP; e++) { p[e] = __expf(l[e] - m); s += p[e]; }
    float inv = 1.f / s;
    #pragma unroll
    for (int e = 0; e < N_EXP; e++) { p[e] *= inv; gate_out[(size_t)t * N_EXP + e] = p[e]; }
    int e1 = 0;
    #pragma unroll
    for (int e = 1; e < N_EXP; e++) if (p[e] > p[e1]) e1 = e;
    int e2 = (e1 == 0) ? 1 : 0;
    #pragma unroll
    for (int e = 0; e < N_EXP; e++) if (e != e1 && p[e] > p[e2]) e2 = e;
    int pos = atomicAdd(cnt + e1, 1);
    tokIdx[(size_t)e1 * T + pos] = t; tokW[(size_t)e1 * T + pos] = p[e1];
    pos = atomicAdd(cnt + e2, 1);
    tokIdx[(size_t)e2 * T + pos] = t; tokW[(size_t)e2 * T + pos] = p[e2];
  }
}

// ---------------- schedule: build row-tile table ----------------
__global__ void schedule_kernel(const int* __restrict__ cnt, int* __restrict__ meta,
                                int* __restrict__ tE, int* __restrict__ tB,
                                int* __restrict__ tV, int T, int maxTiles) {
  if (threadIdx.x != 0 || blockIdx.x != 0) return;
  int t = 0;
  for (int e = 0; e < N_EXP; e++) {
    int c = cnt[e];
    for (int r = 0; r < c && t < maxTiles; r += BM) {
      tE[t] = e; tB[t] = e * T + r; tV[t] = min(BM, c - r); t++;
    }
  }
  meta[0] = t;
}

// ---------------- GEMM1: h = relu(x_bf16 @ W1 + b1)  (grouped) ----------------
__global__ __launch_bounds__(256)
void gemm1_kernel(const unsigned short* __restrict__ xb,
                  const unsigned short* __restrict__ w1t,  // [e][FFC][D_MODEL] bf16
                  const float* __restrict__ b1,
                  const int* __restrict__ meta,
                  const int* __restrict__ tE, const int* __restrict__ tB,
                  const int* __restrict__ tV, const int* __restrict__ tokIdx,
                  unsigned short* __restrict__ h, int FFC, int chunk_off, int ncolLog2) {
  __shared__ unsigned short As[BM * BK];
  __shared__ unsigned short Bs[BN * BK];
  __shared__ int stok[BM];

  // bijective XCD-chunked swizzle over tile-major work ids
  int total = gridDim.x * gridDim.y;
  int L = blockIdx.y * gridDim.x + blockIdx.x;
  int q = total >> 3, r8 = total & 7;
  int xcd = L & 7, idx = L >> 3;
  int work = (xcd < r8) ? (xcd * (q + 1) + idx) : (r8 * (q + 1) + (xcd - r8) * q + idx);
  int ncol = 1 << ncolLog2;
  int tile = work >> ncolLog2;
  int cb = work & (ncol - 1);
  if (tile >= meta[0]) return;
  int e = tE[tile], base = tB[tile], valid = tV[tile];
  int tid = threadIdx.x;

  if (tid < BM) stok[tid] = tokIdx[base + (tid < valid ? tid : valid - 1)];
  __syncthreads();

  int w = tid >> 6, lane = tid & 63;
  int lr = lane >> 3, lc = lane & 7;

  const unsigned short* panel = w1t + (size_t)e * FFC * D_MODEL;
  const unsigned short* aBase[4];
  const unsigned short* bBase[4];
  #pragma unroll
  for (int p = 0; p < 4; p++) {
    int row = (w * 4 + p) * 8 + lr;
    int cA = (lc - row) & 7;
    aBase[p] = xb + (size_t)stok[row] * D_MODEL + cA * 8;
    int cB = (lc - row) & 7;
    bBase[p] = panel + (size_t)(cb * BN + row) * D_MODEL + cB * 8;
  }

  int wr = w >> 1, wc = w & 1;
  int l15 = lane & 15, l4 = lane >> 4;
  int aOff[2][4], bOff[2][4];
  #pragma unroll
  for (int kk = 0; kk < 2; kk++) {
    #pragma unroll
    for (int m = 0; m < 4; m++) {
      int row = wr * 64 + m * 16 + l15;
      int c = kk * 4 + l4;
      aOff[kk][m] = row * 64 + (((c + row) & 7) << 3);
      int col = wc * 64 + m * 16 + l15;
      bOff[kk][m] = col * 64 + (((c + col) & 7) << 3);
    }
  }

  f32x4 acc[4][4];
  #pragma unroll
  for (int m = 0; m < 4; m++)
    #pragma unroll
    for (int n = 0; n < 4; n++) acc[m][n] = (f32x4){0.f, 0.f, 0.f, 0.f};

  for (int kt = 0; kt < D_MODEL / BK; kt++) {
    #pragma unroll
    for (int p = 0; p < 4; p++)
      gl_lds16(aBase[p] + kt * BK, &As[(w * 4 + p) * 512]);
    #pragma unroll
    for (int p = 0; p < 4; p++)
      gl_lds16(bBase[p] + kt * BK, &Bs[(w * 4 + p) * 512]);
    __syncthreads();
    #pragma unroll
    for (int kk = 0; kk < 2; kk++) {
      bf16x8 a[4], b[4];
      #pragma unroll
      for (int m = 0; m < 4; m++) a[m] = *(const bf16x8*)&As[aOff[kk][m]];
      #pragma unroll
      for (int n = 0; n < 4; n++) b[n] = *(const bf16x8*)&Bs[bOff[kk][n]];
      #pragma unroll
      for (int m = 0; m < 4; m++)
        #pragma unroll
        for (int n = 0; n < 4; n++)
          acc[m][n] = __builtin_amdgcn_mfma_f32_16x16x32_bf16(a[m], b[n], acc[m][n], 0, 0, 0);
    }
    __syncthreads();
  }

  #pragma unroll
  for (int n = 0; n < 4; n++) {
    int colc = cb * BN + wc * 64 + n * 16 + l15;
    float bias = b1[(size_t)e * D_FF + chunk_off + colc];
    #pragma unroll
    for (int m = 0; m < 4; m++) {
      #pragma unroll
      for (int r = 0; r < 4; r++) {
        int row = wr * 64 + m * 16 + l4 * 4 + r;
        float v = acc[m][n][r] + bias;
        v = v > 0.f ? v : 0.f;
        h[(size_t)(tile * BM + row) * FFC + colc] = f2bf(v);
      }
    }
  }
}

// ---------------- GEMM2: out += w * (h @ W2 + b2)  (grouped, scatter) ----------------
__global__ __launch_bounds__(256)
void gemm2_kernel(const unsigned short* __restrict__ h,
                  const unsigned short* __restrict__ w2t,  // [e][D_MODEL][FFC] bf16
                  const float* __restrict__ b2,
                  const int* __restrict__ meta,
                  const int* __restrict__ tE, const int* __restrict__ tB,
                  const int* __restrict__ tV, const int* __restrict__ tokIdx,
                  const float* __restrict__ tokW,
                  float* __restrict__ out, int FFC, int chunk_off) {
  __shared__ unsigned short As[BM * BK];
  __shared__ unsigned short Bs[BN * BK];
  __shared__ int stok[BM];
  __shared__ float sw[BM];

  int total = gridDim.x * gridDim.y;
  int L = blockIdx.y * gridDim.x + blockIdx.x;
  int q = total >> 3, r8 = total & 7;
  int xcd = L & 7, idx = L >> 3;
  int work = (xcd < r8) ? (xcd * (q + 1) + idx) : (r8 * (q + 1) + (xcd - r8) * q + idx);
  int tile = work >> 3;          // ncol = 8
  int cb = work & 7;
  if (tile >= meta[0]) return;
  int e = tE[tile], base = tB[tile], valid = tV[tile];
  int tid = threadIdx.x;

  if (tid < BM) {
    int rr = tid < valid ? tid : valid - 1;
    stok[tid] = tokIdx[base + rr];
    sw[tid] = tokW[base + rr];
  }
  __syncthreads();

  int w = tid >> 6, lane = tid & 63;
  int lr = lane >> 3, lc = lane & 7;

  const unsigned short* panel = w2t + (size_t)e * D_MODEL * FFC;
  const unsigned short* aBase[4];
  const unsigned short* bBase[4];
  #pragma unroll
  for (int p = 0; p < 4; p++) {
    int row = (w * 4 + p) * 8 + lr;
    int cA = (lc - row) & 7;
    aBase[p] = h + (size_t)(tile * BM + row) * FFC + cA * 8;
    int cB = (lc - row) & 7;
    bBase[p] = panel + (size_t)(cb * BN + row) * FFC + cB * 8;
  }

  int wr = w >> 1, wc = w & 1;
  int l15 = lane & 15, l4 = lane >> 4;
  int aOff[2][4], bOff[2][4];
  #pragma unroll
  for (int kk = 0; kk < 2; kk++) {
    #pragma unroll
    for (int m = 0; m < 4; m++) {
      int row = wr * 64 + m * 16 + l15;
      int c = kk * 4 + l4;
      aOff[kk][m] = row * 64 + (((c + row) & 7) << 3);
      int col = wc * 64 + m * 16 + l15;
      bOff[kk][m] = col * 64 + (((c + col) & 7) << 3);
    }
  }

  f32x4 acc[4][4];
  #pragma unroll
  for (int m = 0; m < 4; m++)
    #pragma unroll
    for (int n = 0; n < 4; n++) acc[m][n] = (f32x4){0.f, 0.f, 0.f, 0.f};

  int KT = FFC / BK;
  for (int kt = 0; kt < KT; kt++) {
    #pragma unroll
    for (int p = 0; p < 4; p++)
      gl_lds16(aBase[p] + kt * BK, &As[(w * 4 + p) * 512]);
    #pragma unroll
    for (int p = 0; p < 4; p++)
      gl_lds16(bBase[p] + kt * BK, &Bs[(w * 4 + p) * 512]);
    __syncthreads();
    #pragma unroll
    for (int kk = 0; kk < 2; kk++) {
      bf16x8 a[4], b[4];
      #pragma unroll
      for (int m = 0; m < 4; m++) a[m] = *(const bf16x8*)&As[aOff[kk][m]];
      #pragma unroll
      for (int n = 0; n < 4; n++) b[n] = *(const bf16x8*)&Bs[bOff[kk][n]];
      #pragma unroll
      for (int m = 0; m < 4; m++)
        #pragma unroll
        for (int n = 0; n < 4; n++)
          acc[m][n] = __builtin_amdgcn_mfma_f32_16x16x32_bf16(a[m], b[n], acc[m][n], 0, 0, 0);
    }
    __syncthreads();
  }

  int addBias = (chunk_off == 0) ? 1 : 0;
  #pragma unroll
  for (int n = 0; n < 4; n++) {
    int colg = cb * BN + wc * 64 + n * 16 + l15;
    float bias = addBias ? b2[(size_t)e * D_MODEL + colg] : 0.f;
    #pragma unroll
    for (int m = 0; m < 4; m++) {
      #pragma unroll
      for (int r = 0; r < 4; r++) {
        int row = wr * 64 + m * 16 + l4 * 4 + r;
        if (row < valid) {
          float v = (acc[m][n][r] + bias) * sw[row];
          atomicAdd(out + (size_t)stok[row] * D_MODEL + colg, v);
        }
      }
    }
  }
}

// ---------------- host ----------------
extern "C" void kernel_launch(void* const* d_in, const int* in_sizes, int n_in,
                              void* d_out, int out_size, void* d_ws, size_t ws_size,
                              hipStream_t stream) {
  const float* x  = (const float*)d_in[0];
  const float* W1 = (const float*)d_in[1];
  const float* b1 = (const float*)d_in[2];
  const float* W2 = (const float*)d_in[3];
  const float* b2 = (const float*)d_in[4];
  const float* Wg = (const float*)d_in[5];
  const float* bg = (const float*)d_in[6];

  int T = in_sizes[0] / D_MODEL;  // 8192
  float* out = (float*)d_out;
  float* gate_out = out + (size_t)T * D_MODEL;

  char* ws = (char*)d_ws;
  int* cnt  = (int*)(ws + 0);
  int* meta = (int*)(ws + 64);
  int* tE   = (int*)(ws + 128);
  int* tB   = (int*)(ws + 1024);
  int* tV   = (int*)(ws + 2048);
  size_t off = 4096;
  int* tokIdx = (int*)(ws + off);   off += (size_t)N_EXP * T * 4;
  float* tokW = (float*)(ws + off); off += (size_t)N_EXP * T * 4;
  unsigned short* xb = (unsigned short*)(ws + off); off += (size_t)T * D_MODEL * 2;
  off = (off + 255) & ~(size_t)255;

  int maxTiles = (2 * T) / BM + N_EXP;  // 136
  // per-chunk buffers: w1t (8*FFC*1024*2) + w2t (8*1024*FFC*2) + h (maxTiles*128*FFC*2)
  int FFC = D_FF;
  while (FFC > 256 &&
         off + (size_t)FFC * (16384 + 16384 + (size_t)maxTiles * BM * 2) > ws_size)
    FFC >>= 1;

  unsigned short* w1t = (unsigned short*)(ws + off); off += (size_t)FFC * 16384;
  unsigned short* w2t = (unsigned short*)(ws + off); off += (size_t)FFC * 16384;
  unsigned short* h   = (unsigned short*)(ws + off);

  hipMemsetAsync(d_out, 0, (size_t)T * D_MODEL * sizeof(float), stream);
  hipMemsetAsync(cnt, 0, N_EXP * sizeof(int), stream);

  int total8 = T * D_MODEL / 8;
  convert_x_kernel<<<(total8 + 255) / 256, 256, 0, stream>>>(x, xb, total8);
  gating_kernel<<<(T + 3) / 4, 256, 0, stream>>>(x, Wg, bg, gate_out, cnt, tokIdx, tokW, T);
  schedule_kernel<<<1, 64, 0, stream>>>(cnt, meta, tE, tB, tV, T, maxTiles);

  int ncol1Log2 = __builtin_ctz(FFC / BN);
  for (int c = 0; c * FFC < D_FF; c++) {
    transpose_convert_kernel<<<dim3(D_MODEL / 64, FFC / 64, N_EXP), 256, 0, stream>>>(
        W1, w1t, D_MODEL, D_FF, 0, c * FFC, FFC, (unsigned long long)D_MODEL * D_FF);
    transpose_convert_kernel<<<dim3(FFC / 64, D_MODEL / 64, N_EXP), 256, 0, stream>>>(
        W2, w2t, FFC, D_MODEL, c * FFC, 0, D_MODEL, (unsigned long long)D_FF * D_MODEL);
    gemm1_kernel<<<dim3(maxTiles, FFC / BN), 256, 0, stream>>>(
        xb, w1t, b1, meta, tE, tB, tV, tokIdx, h, FFC, c * FFC, ncol1Log2);
    gemm2_kernel<<<dim3(maxTiles, D_MODEL / BN), 256, 0, stream>>>(
        h, w2t, b2, meta, tE, tB, tV, tokIdx, tokW, out, FFC, c * FFC);
  }
}